// Round 6
// baseline (99.250 us; speedup 1.0000x reference)
//
#include <hip/hip_runtime.h>

// DiceLoss: input [N=32, C=4, H=512, W=512] f32, target [N,1,H,W] i32.
// softmax over C; since softmax sums to 1, cardinality = 2*HW exactly, so
// loss = 1 - (2/(N*(2*HW+eps))) * sum_{all pixels} probs[target].
//
// Single fused kernel, fixed geometry (2048 blk x 256 thr x 4 iters covers
// all N*HW/4 float4-groups exactly). R4 lesson: hoisted float4 ARRAYS with
// reinterpret_cast element access defeated SROA -> scratch (VGPR=44, 161us).
// This version uses only NAMED float4/int4 registers accessed via .x/.y/.z/.w.
// (R5 lesson: macro suffixes must not start with a digit — `0.x` lexes as one
// pp-number token and breaks ## pasting. Suffixes are c0..c3/tg now.)

constexpr int N_   = 32;
constexpr int C_   = 4;
constexpr int HW_  = 512 * 512;                 // 2^18
constexpr float EPSF = 1e-6f;

constexpr int NBLK  = 2048;
constexpr int NTHR  = 256;
constexpr int TOTTH = NBLK * NTHR;              // 524288 threads
constexpr int NGROUPS = N_ * HW_ / 4;           // 2097152 float4-groups
static_assert(4 * TOTTH == NGROUPS, "geometry must tile exactly");

__device__ __forceinline__ float px(float a, float b, float c, float d, int t) {
    float m  = fmaxf(fmaxf(a, b), fmaxf(c, d));
    float ea = __expf(a - m);
    float eb = __expf(b - m);
    float ec = __expf(c - m);
    float ed = __expf(d - m);
    float denom = (ea + eb) + (ec + ed);
    float et = (t == 0) ? ea : (t == 1) ? eb : (t == 2) ? ec : ed;
    return et * __builtin_amdgcn_rcpf(denom);   // approx rcp: ~1e-6 rel err
}

__global__ __launch_bounds__(NTHR) void dice_fused(
        const float* __restrict__ x,
        const int*   __restrict__ tgt,
        float*       __restrict__ partial,      // d_ws[0 .. NBLK)
        unsigned*    __restrict__ ticket,       // d_ws + NBLK floats
        float*       __restrict__ out) {
    const int tid = blockIdx.x * NTHR + threadIdx.x;

    // ---- phase 1: issue ALL loads into NAMED registers (20 x 16B) ----
#define ADDRS(K, IT)                                                         \
    const int  pix##K = (tid + (IT) * TOTTH) << 2;                           \
    const int  n##K   = pix##K >> 18;                                        \
    const int  hw##K  = pix##K & (HW_ - 1);                                  \
    const float* b##K = x + (size_t)n##K * (C_ * HW_) + hw##K;               \
    const int*   g##K = tgt + (size_t)n##K * HW_ + hw##K;

    ADDRS(A, 0) ADDRS(B, 1) ADDRS(C, 2) ADDRS(D, 3)

#define LOADS(K)                                                             \
    float4 v##K##c0 = *reinterpret_cast<const float4*>(b##K);                \
    float4 v##K##c1 = *reinterpret_cast<const float4*>(b##K + HW_);          \
    float4 v##K##c2 = *reinterpret_cast<const float4*>(b##K + 2 * HW_);      \
    float4 v##K##c3 = *reinterpret_cast<const float4*>(b##K + 3 * HW_);      \
    int4   v##K##tg = *reinterpret_cast<const int4*>(g##K);

    LOADS(A) LOADS(B) LOADS(C) LOADS(D)

    // ---- phase 2: compute, members only (no address-taking) ----
    float acc = 0.f;
#define GROUP(K)                                                              \
    acc += px(v##K##c0.x, v##K##c1.x, v##K##c2.x, v##K##c3.x, v##K##tg.x);    \
    acc += px(v##K##c0.y, v##K##c1.y, v##K##c2.y, v##K##c3.y, v##K##tg.y);    \
    acc += px(v##K##c0.z, v##K##c1.z, v##K##c2.z, v##K##c3.z, v##K##tg.z);    \
    acc += px(v##K##c0.w, v##K##c1.w, v##K##c2.w, v##K##c3.w, v##K##tg.w);

    GROUP(A) GROUP(B) GROUP(C) GROUP(D)
#undef ADDRS
#undef LOADS
#undef GROUP

    // ---- phase 3: block reduction (fixed order -> deterministic) ----
    #pragma unroll
    for (int off = 32; off > 0; off >>= 1)
        acc += __shfl_down(acc, off, 64);

    __shared__ float wsum[NTHR / 64];
    __shared__ int   lastFlag;
    const int lane = threadIdx.x & 63;
    const int wid  = threadIdx.x >> 6;
    if (lane == 0) wsum[wid] = acc;
    __syncthreads();

    if (threadIdx.x == 0) {
        float bs = (wsum[0] + wsum[1]) + (wsum[2] + wsum[3]);
        atomicExch(reinterpret_cast<unsigned*>(&partial[blockIdx.x]),
                   __float_as_uint(bs));
        __threadfence();
        unsigned old = atomicAdd(ticket, 1u);
        lastFlag = (old == (unsigned)(NBLK - 1));
    }
    __syncthreads();

    // ---- phase 4: last block reduces all partials in fixed order ----
    if (lastFlag) {
        __threadfence();
        float a = 0.f;
        #pragma unroll
        for (int r = 0; r < NBLK / NTHR; ++r) {
            int i = r * NTHR + threadIdx.x;  // fixed order per thread
            a += __uint_as_float(
                atomicAdd(reinterpret_cast<unsigned*>(&partial[i]), 0u));
        }
        #pragma unroll
        for (int off = 32; off > 0; off >>= 1)
            a += __shfl_down(a, off, 64);
        if (lane == 0) wsum[wid] = a;
        __syncthreads();
        if (threadIdx.x == 0) {
            float S    = (wsum[0] + wsum[1]) + (wsum[2] + wsum[3]);
            float card = 2.0f * (float)HW_ + EPSF;
            out[0] = 1.0f - 2.0f * S / ((float)N_ * card);
        }
    }
}

extern "C" void kernel_launch(void* const* d_in, const int* in_sizes, int n_in,
                              void* d_out, int out_size, void* d_ws, size_t ws_size,
                              hipStream_t stream) {
    const float* x   = (const float*)d_in[0];
    const int*   tgt = (const int*)d_in[1];
    float*       out = (float*)d_out;

    float*    partial = (float*)d_ws;
    unsigned* ticket  = (unsigned*)((char*)d_ws + (size_t)NBLK * sizeof(float));

    hipMemsetAsync(ticket, 0, sizeof(unsigned), stream);
    dice_fused<<<NBLK, NTHR, 0, stream>>>(x, tgt, partial, ticket, out);
}

// Round 7
// 33.515 us; speedup vs baseline: 2.9614x; 2.9614x over previous
//
#include <hip/hip_runtime.h>

// DiceLoss: input [N=32, C=4, H=512, W=512] f32, target [N,1,H,W] i32.
// softmax over C; since softmax sums to 1, cardinality = 2*HW exactly, so
// loss = 1 - (2/(N*(2*HW+eps))) * sum_{all pixels} probs[target].
//
// R4/R6 lesson: single-dispatch fusion via ticket + __threadfence() costs
// ~125us — the device-scope release fence does an L2 writeback per block
// (2048x), serializing the whole dispatch (time was identical whether data
// came from HBM or L3 => not a BW effect). Two plain-store dispatches (R3,
// 33.7us) are the right structure; kernel boundary provides coherence.
//
// This round vs R3: compile-time trip count (4 iters) so the compiler can
// software-pipeline loads across iterations at its own register budget, and
// v_rcp_f32 instead of the IEEE divide sequence.

constexpr int N_   = 32;
constexpr int C_   = 4;
constexpr int HW_  = 512 * 512;                 // 2^18
constexpr float EPSF = 1e-6f;

constexpr int NBLK  = 2048;
constexpr int NTHR  = 256;
constexpr int TOTTH = NBLK * NTHR;              // 524288 threads
constexpr int NGROUPS = N_ * HW_ / 4;           // 2097152 float4-groups
constexpr int NITER = NGROUPS / TOTTH;          // exactly 4
static_assert(NITER * TOTTH == NGROUPS, "geometry must tile exactly");

__device__ __forceinline__ float px(float a, float b, float c, float d, int t) {
    float m  = fmaxf(fmaxf(a, b), fmaxf(c, d));
    float ea = __expf(a - m);
    float eb = __expf(b - m);
    float ec = __expf(c - m);
    float ed = __expf(d - m);
    float denom = (ea + eb) + (ec + ed);
    float et = (t == 0) ? ea : (t == 1) ? eb : (t == 2) ? ec : ed;
    return et * __builtin_amdgcn_rcpf(denom);   // ~1e-6 rel err, threshold 1.5e-2
}

__global__ __launch_bounds__(NTHR) void dice_partial(
        const float* __restrict__ x,
        const int*   __restrict__ tgt,
        float*       __restrict__ partial) {
    const int tid = blockIdx.x * NTHR + threadIdx.x;
    float acc = 0.f;

    #pragma unroll
    for (int it = 0; it < NITER; ++it) {
        const int pix = (tid + it * TOTTH) << 2;   // 4 pixels per group
        const int n   = pix >> 18;                 // / HW_
        const int hw  = pix & (HW_ - 1);
        const float* base = x + (size_t)n * (C_ * HW_) + hw;

        float4 v0 = *reinterpret_cast<const float4*>(base);
        float4 v1 = *reinterpret_cast<const float4*>(base + HW_);
        float4 v2 = *reinterpret_cast<const float4*>(base + 2 * HW_);
        float4 v3 = *reinterpret_cast<const float4*>(base + 3 * HW_);
        int4   t4 = *reinterpret_cast<const int4*>(tgt + (size_t)n * HW_ + hw);

        acc += px(v0.x, v1.x, v2.x, v3.x, t4.x);
        acc += px(v0.y, v1.y, v2.y, v3.y, t4.y);
        acc += px(v0.z, v1.z, v2.z, v3.z, t4.z);
        acc += px(v0.w, v1.w, v2.w, v3.w, t4.w);
    }

    // wave (64-lane) reduce, fixed order -> deterministic
    #pragma unroll
    for (int off = 32; off > 0; off >>= 1)
        acc += __shfl_down(acc, off, 64);

    __shared__ float wsum[NTHR / 64];
    const int lane = threadIdx.x & 63;
    const int wid  = threadIdx.x >> 6;
    if (lane == 0) wsum[wid] = acc;
    __syncthreads();
    if (threadIdx.x == 0)
        partial[blockIdx.x] = (wsum[0] + wsum[1]) + (wsum[2] + wsum[3]);
}

__global__ __launch_bounds__(NTHR) void dice_final(
        const float* __restrict__ partial, float* __restrict__ out) {
    float acc = 0.f;
    #pragma unroll
    for (int r = 0; r < NBLK / NTHR; ++r)
        acc += partial[r * NTHR + threadIdx.x];   // fixed order per thread

    #pragma unroll
    for (int off = 32; off > 0; off >>= 1)
        acc += __shfl_down(acc, off, 64);

    __shared__ float wsum[NTHR / 64];
    const int lane = threadIdx.x & 63;
    const int wid  = threadIdx.x >> 6;
    if (lane == 0) wsum[wid] = acc;
    __syncthreads();
    if (threadIdx.x == 0) {
        float S    = (wsum[0] + wsum[1]) + (wsum[2] + wsum[3]);
        float card = 2.0f * (float)HW_ + EPSF;
        out[0] = 1.0f - 2.0f * S / ((float)N_ * card);
    }
}

extern "C" void kernel_launch(void* const* d_in, const int* in_sizes, int n_in,
                              void* d_out, int out_size, void* d_ws, size_t ws_size,
                              hipStream_t stream) {
    const float* x   = (const float*)d_in[0];
    const int*   tgt = (const int*)d_in[1];
    float*       out = (float*)d_out;
    float*       par = (float*)d_ws;

    dice_partial<<<NBLK, NTHR, 0, stream>>>(x, tgt, par);
    dice_final<<<1, NTHR, 0, stream>>>(par, out);
}